// Round 21
// baseline (129.093 us; speedup 1.0000x reference)
//
#include <hip/hip_runtime.h>

#define BATCH   4096
#define IN_F    1024
#define OUT_F   1024
#define KF      8
#define KD      14336          /* K-dim in i8 elements (= bytes), feature-major, k=0 trimmed */

#define BM 256
#define BN 256
#define BK 64                  /* K per tile (bytes) */
#define KSPLIT 4
#define KCHUNK (KD/KSPLIT)     /* 3584 */
#define NT (KCHUNK/BK)         /* 56 K-tiles per block */
#define C_ELEMS ((size_t)BATCH * OUT_F)

#define QW 1040384.0f          /* 127 * 8192: w stored as raw/8192 -> q = rint(w*QW) */
#define DQ (1.0f/132128768.0f) /* 1/(127*127*8192) */

typedef int   i32x4 __attribute__((ext_vector_type(4)));
typedef float f32x4 __attribute__((ext_vector_type(4)));

__device__ __forceinline__ void gload_lds16(const void* g, void* l) {
  __builtin_amdgcn_global_load_lds((const __attribute__((address_space(1))) void*)g,
                                   (__attribute__((address_space(3))) void*)l,
                                   16, 0, 0);
}

__device__ __forceinline__ unsigned int pack4(int q0, int q1, int q2, int q3) {
  return (unsigned int)(q0 & 255) | ((unsigned int)(q1 & 255) << 8) |
         ((unsigned int)(q2 & 255) << 16) | ((unsigned int)(q3 & 255) << 24);
}

// ---------------- W quantization (k=0 trimmed, feature-major, i-quad) + bias ----------------
__global__ __launch_bounds__(256) void wconv_kernel(const float* __restrict__ a,
                                                    const float* __restrict__ b,
                                                    signed char* __restrict__ W,
                                                    float* __restrict__ bias) {
  const int o  = blockIdx.x;
  const int i0 = threadIdx.x * 4;
  const float4* ap = reinterpret_cast<const float4*>(a + (size_t)o * 8192 + i0 * 8);
  const float4* bp = reinterpret_cast<const float4*>(b + (size_t)o * 8192 + i0 * 8);
  union { float4 v[2]; float f[8]; } ua[4], ub[4];
#pragma unroll
  for (int ii = 0; ii < 4; ++ii) {
    ua[ii].v[0] = ap[2 * ii]; ua[ii].v[1] = ap[2 * ii + 1];
    ub[ii].v[0] = bp[2 * ii]; ub[ii].v[1] = bp[2 * ii + 1];
  }
  unsigned int* wp = reinterpret_cast<unsigned int*>(W + (size_t)o * KD + i0);
#pragma unroll
  for (int j = 0; j < 7; ++j) {
    int qa[4], qb[4];
#pragma unroll
    for (int ii = 0; ii < 4; ++ii) {
      qa[ii] = __float2int_rn(ua[ii].f[j + 1] * QW);
      qb[ii] = __float2int_rn(ub[ii].f[j + 1] * QW);
    }
    wp[j       * (IN_F / 4)] = pack4(qa[0], qa[1], qa[2], qa[3]);
    wp[(7 + j) * (IN_F / 4)] = pack4(qb[0], qb[1], qb[2], qb[3]);
  }
  float bsum = ub[0].f[0] + ub[1].f[0] + ub[2].f[0] + ub[3].f[0];
#pragma unroll
  for (int off = 32; off > 0; off >>= 1) bsum += __shfl_down(bsum, off);
  __shared__ float red[4];
  if ((threadIdx.x & 63) == 0) red[threadIdx.x >> 6] = bsum;
  __syncthreads();
  if (threadIdx.x == 0) bias[o] = red[0] + red[1] + red[2] + red[3];
}

// ---------------- feature kernel (feature-major, i-quad): Xq[b][j*1024+i] i8 ----------------
__global__ __launch_bounds__(256) void feat_kernel(const float* __restrict__ x,
                                                   signed char* __restrict__ Xq) {
  int idx = blockIdx.x * 256 + threadIdx.x;
  int bb = idx >> 8;
  int i0 = (idx & 255) * 4;
  float4 xv = *reinterpret_cast<const float4*>(x + (size_t)bb * IN_F + i0);
  float sv[4][KF], cv[4][KF];
#pragma unroll
  for (int ii = 0; ii < 4; ++ii) {
    float xx = (ii == 0) ? xv.x : (ii == 1) ? xv.y : (ii == 2) ? xv.z : xv.w;
    sincosf(xx, &sv[ii][1], &cv[ii][1]);
#pragma unroll
    for (int k = 2; k < KF; ++k) {
      sv[ii][k] = sv[ii][k-1] * cv[ii][1] + cv[ii][k-1] * sv[ii][1];
      cv[ii][k] = cv[ii][k-1] * cv[ii][1] - sv[ii][k-1] * sv[ii][1];
    }
  }
  unsigned int* dst = reinterpret_cast<unsigned int*>(Xq + (size_t)bb * KD + i0);
#pragma unroll
  for (int j = 0; j < 7; ++j) {
    dst[j * (IN_F / 4)] = pack4(__float2int_rn(127.f * sv[0][j+1]), __float2int_rn(127.f * sv[1][j+1]),
                                __float2int_rn(127.f * sv[2][j+1]), __float2int_rn(127.f * sv[3][j+1]));
    dst[(7 + j) * (IN_F / 4)] = pack4(__float2int_rn(127.f * cv[0][j+1]), __float2int_rn(127.f * cv[1][j+1]),
                                      __float2int_rn(127.f * cv[2][j+1]), __float2int_rn(127.f * cv[3][j+1]));
  }
}

// ---------------- GEMM: i8 256x256, 8 waves, sB triple-buffered, 1 barrier/tile ----------
// R20 (2-barrier merged, 74.6us) minus the mid-tile BAR1 + lgkmcnt(0) drain: those
// existed only for the sB[cur] WAR under 2-buffer/2-ahead staging. sB[3] (LDS 80KB,
// still 1 block/CU at grid=256) puts B(t+2) in a buffer nobody reads -> per tile:
// {4 gloads (A(t+1), B(t+2)) + 12 ds_reads + 32 MFMA (compiler counted-lgkm waits force
// reads complete) + vmcnt(2) + s_barrier}. WAR audit: tile t+1's A-stage overwrites
// sA[read@t] and B-stage overwrites sB[read@t] -- both ordered by the tile-t barrier,
// which every wave reaches only after its reads are lgkm-complete (MFMA consumption).
// vmcnt ledger (4 gloads/tile, A then B): 6 outstanding at tile end, vmcnt(2) retires
// A(t+1)+B(t+1), B(t+2) stays in flight -- identical counts to R12/R20, NEVER 0
// (the R4 killer was vmcnt(0) full drain; this is the counted variant).
// Buffer rotation via named pointers (rule #20). Pre-commit: GEMM >= 74.5us -> revert R20.
__global__ __launch_bounds__(512, 2) void gemm_kernel(const signed char* __restrict__ A,
                                                      const signed char* __restrict__ Bt,
                                                      int* __restrict__ Cout,
                                                      int use_slab) {
  __shared__ signed char sA[2][BM * BK];   // 16 KiB each
  __shared__ signed char sB[3][BN * BK];   // 16 KiB each (triple buffer)

  const int tid  = threadIdx.x;
  const int wid  = tid >> 6;
  const int lane = tid & 63;
  const int wm = wid >> 2, wn = wid & 3;
  const int l15 = lane & 15;

  // bijective XCD swizzle: 256 blocks % 8 XCDs == 0; 32 consecutive work items/XCD
  const int bid = blockIdx.x;
  const int s   = (bid & 7) * 32 + (bid >> 3);
  const int z   = s >> 6;          // K-split chunk 0..3
  const int mt  = s & 15;          // m-tile fastest -> XCD shares W panels in L2
  const int nt  = (s >> 4) & 3;
  const int m0  = mt * BM;
  const int n0  = nt * BN;
  const int fbase = z * KCHUNK;

  // ---- staging addressing: 4 lanes/row (16B granules), 16 rows/wave, 128 rows/gload ----
  const int srow = wid * 16 + (lane >> 2);                 // row 0..127 within group
  const int swz  = ((lane >> 2) & 3) ^ ((lane >> 4) & 3);  // s(row) = (r&3)^((r>>2)&3)
  const int gsrc = (lane & 3) ^ swz;                       // pre-swizzled source granule
  const signed char* pA = A  + (size_t)(m0 + srow) * KD + fbase + gsrc * 16;
  const signed char* pB = Bt + (size_t)(n0 + srow) * KD + fbase + gsrc * 16;
  const int ldst = wid * 1024;                             // byte offset in 8KB group

  // ---- fragment read addressing (swizzled): row r, granule (lane>>4)^s(r&15) ----
  const int rswz = (l15 & 3) ^ ((l15 >> 2) & 3);
  const int kgr  = (((lane >> 4) ^ rswz) & 3) * 16;        // byte offset within 64B row
  const int arowb = (wm * 128 + l15) * BK;                 // byte base, mf stride 16*BK
  const int browb = (wn * 64 + l15) * BK;

  i32x4 acc[8][4] = {};

  // ---- prologue: A(0)->sA[0], B(0)->sB[0], B(1)->sB[1]; retire A0,B0 (B1 in flight) ----
  gload_lds16(pA,                         &sA[0][ldst]);
  gload_lds16(pA + (size_t)128 * KD,      &sA[0][8192 + ldst]);
  gload_lds16(pB,                         &sB[0][ldst]);
  gload_lds16(pB + (size_t)128 * KD,      &sB[0][8192 + ldst]);
  gload_lds16(pB + BK,                    &sB[1][ldst]);
  gload_lds16(pB + (size_t)128 * KD + BK, &sB[1][8192 + ldst]);
  asm volatile("s_waitcnt vmcnt(2)" ::: "memory");
  asm volatile("s_barrier" ::: "memory");

  // named rotating buffer pointers (rule #20: no runtime-indexed register arrays)
  signed char* aR = &sA[0][0];  signed char* aS = &sA[1][0];
  signed char* bR = &sB[0][0];  signed char* bN = &sB[1][0];  signed char* bS = &sB[2][0];

  for (int t = 0; t < NT; ++t) {
    const int kA = (t + 1 < NT) ? (t + 1) * BK : 0;   // dead-wrap keeps ledger uniform
    const int kB = (t + 2 < NT) ? (t + 2) * BK : 0;

    // stage A(t+1)->aS, B(t+2)->bS (both buffers WAR-free: readers drained pre-barrier)
    gload_lds16(pA + kA,                      aS + ldst);
    gload_lds16(pA + (size_t)128 * KD + kA,   aS + 8192 + ldst);
    gload_lds16(pB + kB,                      bS + ldst);
    gload_lds16(pB + (size_t)128 * KD + kB,   bS + 8192 + ldst);

    // read tile t fragments (compiler emits counted lgkm waits before each MFMA use)
    i32x4 af[8], bfr[4];
#pragma unroll
    for (int f = 0; f < 8; ++f)
      af[f] = *reinterpret_cast<const i32x4*>(aR + arowb + f * (16 * BK) + kgr);
#pragma unroll
    for (int nf = 0; nf < 4; ++nf)
      bfr[nf] = *reinterpret_cast<const i32x4*>(bR + browb + nf * (16 * BK) + kgr);

    __builtin_amdgcn_s_setprio(1);
#pragma unroll
    for (int f = 0; f < 8; ++f)
#pragma unroll
      for (int nf = 0; nf < 4; ++nf)
        acc[f][nf] = __builtin_amdgcn_mfma_i32_16x16x64_i8(af[f], bfr[nf], acc[f][nf], 0, 0, 0);
    __builtin_amdgcn_s_setprio(0);

    // counted publish: retire A(t+1)+B(t+1); B(t+2) stays in flight (never 0)
    asm volatile("s_waitcnt vmcnt(2)" ::: "memory");
    asm volatile("s_barrier" ::: "memory");

    // rotate buffers: A swap; B (read, next, stage) -> (next, stage, read)
    signed char* tA = aR; aR = aS; aS = tA;
    signed char* tB = bR; bR = bN; bN = bS; bS = tB;
  }

  // ---- epilogue (C/D layout dtype-independent: col=l15, row=(lane>>4)*4+jj) ----
  const int crow = m0 + wm * 128 + (lane >> 4) * 4;
  const int ccol = n0 + wn * 64 + l15;
  if (use_slab) {
    int* Cz = Cout + (size_t)z * C_ELEMS;
#pragma unroll
    for (int mf = 0; mf < 8; ++mf)
#pragma unroll
      for (int nf = 0; nf < 4; ++nf)
#pragma unroll
        for (int jj = 0; jj < 4; ++jj)
          Cz[(size_t)(crow + mf * 16 + jj) * OUT_F + ccol + nf * 16] = acc[mf][nf][jj];
  } else {
    float* Cf = reinterpret_cast<float*>(Cout);
#pragma unroll
    for (int mf = 0; mf < 8; ++mf)
#pragma unroll
      for (int nf = 0; nf < 4; ++nf)
#pragma unroll
        for (int jj = 0; jj < 4; ++jj)
          atomicAdd(&Cf[(size_t)(crow + mf * 16 + jj) * OUT_F + ccol + nf * 16],
                    (float)acc[mf][nf][jj] * DQ);
  }
}

// ---------------- K-split i32 slab reduce + dequant + bias ----------------
__global__ __launch_bounds__(256) void reduce_kernel(const i32x4* __restrict__ s,
                                                     const float* __restrict__ bias,
                                                     f32x4* __restrict__ y) {
  size_t i = (size_t)blockIdx.x * 256 + threadIdx.x;
  const size_t NQ = C_ELEMS / 4;
  i32x4 v = s[i] + s[i + NQ] + s[i + 2 * NQ] + s[i + 3 * NQ];
  f32x4 bv = reinterpret_cast<const f32x4*>(bias)[i & 255];   // OUT_F/4 = 256 per row
  f32x4 r;
  r[0] = (float)v[0] * DQ + bv[0];
  r[1] = (float)v[1] * DQ + bv[1];
  r[2] = (float)v[2] * DQ + bv[2];
  r[3] = (float)v[3] * DQ + bv[3];
  y[i] = r;
}

// ---------------- bias broadcast (atomic-fallback init): y[b][o] = bias[o] ----------------
__global__ __launch_bounds__(256) void binit_kernel(const float* __restrict__ bias,
                                                    f32x4* __restrict__ y) {
  size_t i = (size_t)blockIdx.x * 256 + threadIdx.x;
  y[i] = reinterpret_cast<const f32x4*>(bias)[i & 255];
}

// ---------------- fallback (no workspace): direct f32 evaluation ----------------
__global__ __launch_bounds__(256) void naive_kernel(const float* __restrict__ x,
                                                    const float* __restrict__ a,
                                                    const float* __restrict__ b,
                                                    float* __restrict__ y) {
  int o  = blockIdx.x * 256 + threadIdx.x;
  int bb = blockIdx.y;
  __shared__ float xs[IN_F];
  for (int i = threadIdx.x; i < IN_F; i += 256) xs[i] = x[(size_t)bb * IN_F + i];
  __syncthreads();
  float acc = 0.f;
  for (int i = 0; i < IN_F; ++i) {
    float s1, c1; sincosf(xs[i], &s1, &c1);
    float sk = 0.f, ck = 1.f;
    const float* ap = a + (size_t)o * 8192 + i * KF;
    const float* bp = b + (size_t)o * 8192 + i * KF;
#pragma unroll
    for (int k = 0; k < KF; ++k) {
      acc += sk * ap[k] + ck * bp[k];
      float sn = sk * c1 + ck * s1;
      ck = ck * c1 - sk * s1;
      sk = sn;
    }
  }
  y[(size_t)bb * OUT_F + o] = acc;
}

extern "C" void kernel_launch(void* const* d_in, const int* in_sizes, int n_in,
                              void* d_out, int out_size, void* d_ws, size_t ws_size,
                              hipStream_t stream) {
  (void)in_sizes; (void)n_in; (void)out_size;
  const float* x = (const float*)d_in[0];
  const float* a = (const float*)d_in[1];
  const float* b = (const float*)d_in[2];
  float* y = (float*)d_out;

  const size_t XQ_BYTES   = (size_t)BATCH * KD;                            // 56 MiB
  const size_t WQ_BYTES   = (size_t)OUT_F * KD;                            // 14 MiB
  const size_t BIAS_BYTES = (size_t)OUT_F * sizeof(float);                 // 4 KiB
  const size_t SLAB_BYTES = C_ELEMS * sizeof(int) * KSPLIT;                // 64 MiB

  if (ws_size >= XQ_BYTES + WQ_BYTES + BIAS_BYTES) {
    signed char* Xq = (signed char*)d_ws;
    signed char* Wq = (signed char*)d_ws + XQ_BYTES;
    float* bias     = (float*)((char*)d_ws + XQ_BYTES + WQ_BYTES);
    int* slabs      = (int*)((char*)d_ws + XQ_BYTES + WQ_BYTES + BIAS_BYTES);
    const bool slab = ws_size >= XQ_BYTES + WQ_BYTES + BIAS_BYTES + SLAB_BYTES;

    wconv_kernel<<<OUT_F, 256, 0, stream>>>(a, b, Wq, bias);
    feat_kernel<<<(BATCH * IN_F / 4) / 256, 256, 0, stream>>>(x, Xq);
    if (slab) {
      gemm_kernel<<<dim3((BATCH / BM) * (OUT_F / BN) * KSPLIT), 512, 0, stream>>>(Xq, Wq, slabs, 1);
      reduce_kernel<<<(int)(C_ELEMS / 4 / 256), 256, 0, stream>>>((const i32x4*)slabs, bias, (f32x4*)y);
    } else {
      binit_kernel<<<(int)(C_ELEMS / 4 / 256), 256, 0, stream>>>(bias, (f32x4*)y);
      gemm_kernel<<<dim3((BATCH / BM) * (OUT_F / BN) * KSPLIT), 512, 0, stream>>>(Xq, Wq, (int*)y, 0);
    }
  } else {
    naive_kernel<<<dim3(OUT_F / 256, BATCH), 256, 0, stream>>>(x, a, b, y);
  }
}

// Round 22
// 112.998 us; speedup vs baseline: 1.1424x; 1.1424x over previous
//
#include <hip/hip_runtime.h>

#define BATCH   4096
#define IN_F    1024
#define OUT_F   1024
#define KF      8
#define KD      14336          /* K-dim in i8 elements (= bytes), feature-major, k=0 trimmed */

#define BM 256
#define BN 256
#define BK 64                  /* K per tile (bytes) */
#define KSPLIT 4
#define KCHUNK (KD/KSPLIT)     /* 3584 */
#define NT (KCHUNK/BK)         /* 56 K-tiles per block (even) */
#define C_ELEMS ((size_t)BATCH * OUT_F)

#define QW 1040384.0f          /* 127 * 8192: w stored as raw/8192 -> q = rint(w*QW) */
#define DQ (1.0f/132128768.0f) /* 1/(127*127*8192) */

typedef int   i32x4 __attribute__((ext_vector_type(4)));
typedef float f32x4 __attribute__((ext_vector_type(4)));

__device__ __forceinline__ void gload_lds16(const void* g, void* l) {
  __builtin_amdgcn_global_load_lds((const __attribute__((address_space(1))) void*)g,
                                   (__attribute__((address_space(3))) void*)l,
                                   16, 0, 0);
}

__device__ __forceinline__ unsigned int pack4(int q0, int q1, int q2, int q3) {
  return (unsigned int)(q0 & 255) | ((unsigned int)(q1 & 255) << 8) |
         ((unsigned int)(q2 & 255) << 16) | ((unsigned int)(q3 & 255) << 24);
}

// ---------------- W quantization (k=0 trimmed, feature-major, i-quad) + bias ----------------
__global__ __launch_bounds__(256) void wconv_kernel(const float* __restrict__ a,
                                                    const float* __restrict__ b,
                                                    signed char* __restrict__ W,
                                                    float* __restrict__ bias) {
  const int o  = blockIdx.x;
  const int i0 = threadIdx.x * 4;
  const float4* ap = reinterpret_cast<const float4*>(a + (size_t)o * 8192 + i0 * 8);
  const float4* bp = reinterpret_cast<const float4*>(b + (size_t)o * 8192 + i0 * 8);
  union { float4 v[2]; float f[8]; } ua[4], ub[4];
#pragma unroll
  for (int ii = 0; ii < 4; ++ii) {
    ua[ii].v[0] = ap[2 * ii]; ua[ii].v[1] = ap[2 * ii + 1];
    ub[ii].v[0] = bp[2 * ii]; ub[ii].v[1] = bp[2 * ii + 1];
  }
  unsigned int* wp = reinterpret_cast<unsigned int*>(W + (size_t)o * KD + i0);
#pragma unroll
  for (int j = 0; j < 7; ++j) {
    int qa[4], qb[4];
#pragma unroll
    for (int ii = 0; ii < 4; ++ii) {
      qa[ii] = __float2int_rn(ua[ii].f[j + 1] * QW);
      qb[ii] = __float2int_rn(ub[ii].f[j + 1] * QW);
    }
    wp[j       * (IN_F / 4)] = pack4(qa[0], qa[1], qa[2], qa[3]);
    wp[(7 + j) * (IN_F / 4)] = pack4(qb[0], qb[1], qb[2], qb[3]);
  }
  float bsum = ub[0].f[0] + ub[1].f[0] + ub[2].f[0] + ub[3].f[0];
#pragma unroll
  for (int off = 32; off > 0; off >>= 1) bsum += __shfl_down(bsum, off);
  __shared__ float red[4];
  if ((threadIdx.x & 63) == 0) red[threadIdx.x >> 6] = bsum;
  __syncthreads();
  if (threadIdx.x == 0) bias[o] = red[0] + red[1] + red[2] + red[3];
}

// ---------------- feature kernel (feature-major, i-quad): Xq[b][j*1024+i] i8 ----------------
__global__ __launch_bounds__(256) void feat_kernel(const float* __restrict__ x,
                                                   signed char* __restrict__ Xq) {
  int idx = blockIdx.x * 256 + threadIdx.x;
  int bb = idx >> 8;
  int i0 = (idx & 255) * 4;
  float4 xv = *reinterpret_cast<const float4*>(x + (size_t)bb * IN_F + i0);
  float sv[4][KF], cv[4][KF];
#pragma unroll
  for (int ii = 0; ii < 4; ++ii) {
    float xx = (ii == 0) ? xv.x : (ii == 1) ? xv.y : (ii == 2) ? xv.z : xv.w;
    sincosf(xx, &sv[ii][1], &cv[ii][1]);
#pragma unroll
    for (int k = 2; k < KF; ++k) {
      sv[ii][k] = sv[ii][k-1] * cv[ii][1] + cv[ii][k-1] * sv[ii][1];
      cv[ii][k] = cv[ii][k-1] * cv[ii][1] - sv[ii][k-1] * sv[ii][1];
    }
  }
  unsigned int* dst = reinterpret_cast<unsigned int*>(Xq + (size_t)bb * KD + i0);
#pragma unroll
  for (int j = 0; j < 7; ++j) {
    dst[j * (IN_F / 4)] = pack4(__float2int_rn(127.f * sv[0][j+1]), __float2int_rn(127.f * sv[1][j+1]),
                                __float2int_rn(127.f * sv[2][j+1]), __float2int_rn(127.f * sv[3][j+1]));
    dst[(7 + j) * (IN_F / 4)] = pack4(__float2int_rn(127.f * cv[0][j+1]), __float2int_rn(127.f * cv[1][j+1]),
                                      __float2int_rn(127.f * cv[2][j+1]), __float2int_rn(127.f * cv[3][j+1]));
  }
}

// ---------------- GEMM: i8 256x256, 8 waves, MERGED 1-phase/tile, 2 barriers/tile ----------
// FINAL (best of R0-R21, 112.5us total / 74.6us GEMM): R12 skeleton with Q0+Q1 merged.
// Per tile: {12 ds_reads (af x8 + bf x4) + A-stage(2) + lgkmcnt(0) + BAR1 + B-stage(2) +
// 32 MFMA + vmcnt(2) + BAR2}. Counted-vmcnt ledger: 6 outstanding max, retire 4 at
// vmcnt(2), 2-tile lead, never 0 in loop. T2 swizzle via pre-swizzled global source +
// swizzled ds_read (2-way b128 aliasing = structural floor). i32 acc EXACT.
// Barrier-count curve (measured): 4/tile=79us (R12), 2/tile=74.6us (THIS), 1/tile=90us
// (R21: mid-tile barrier is the pacing point braiding 8 waves; removing it convoys the
// LDS port), 1/tile+vmcnt(0)=R4 disaster. 2/tile is the optimum.
// Closed ledger: R4/R9 desync -13/-20%; R8 1-wave/SIMD -36%; R10/R16 cross-block TLP
// -50%/-11%; R13 hand-vmcnt asm = WRONG (untracked loads); R14 B reg-direct -20%;
// R18 bf-prefetch null (port-throughput-bound, not latency-bound); R21 1-barrier -17%.
__global__ __launch_bounds__(512, 2) void gemm_kernel(const signed char* __restrict__ A,
                                                      const signed char* __restrict__ Bt,
                                                      int* __restrict__ Cout,
                                                      int use_slab) {
  __shared__ signed char sA[2][BM * BK];   // 16 KiB each
  __shared__ signed char sB[2][BN * BK];

  const int tid  = threadIdx.x;
  const int wid  = tid >> 6;
  const int lane = tid & 63;
  const int wm = wid >> 2, wn = wid & 3;
  const int l15 = lane & 15;

  // bijective XCD swizzle: 256 blocks % 8 XCDs == 0; 32 consecutive work items/XCD
  const int bid = blockIdx.x;
  const int s   = (bid & 7) * 32 + (bid >> 3);
  const int z   = s >> 6;          // K-split chunk 0..3
  const int mt  = s & 15;          // m-tile fastest -> XCD shares W panels in L2
  const int nt  = (s >> 4) & 3;
  const int m0  = mt * BM;
  const int n0  = nt * BN;
  const int fbase = z * KCHUNK;

  // ---- staging addressing: 4 lanes/row (16B granules), 16 rows/wave, 128 rows/gload ----
  const int srow = wid * 16 + (lane >> 2);                 // row 0..127 within group
  const int swz  = ((lane >> 2) & 3) ^ ((lane >> 4) & 3);  // s(row) = (r&3)^((r>>2)&3)
  const int gsrc = (lane & 3) ^ swz;                       // pre-swizzled source granule
  const signed char* pA = A  + (size_t)(m0 + srow) * KD + fbase + gsrc * 16;
  const signed char* pB = Bt + (size_t)(n0 + srow) * KD + fbase + gsrc * 16;
  const int ldst = wid * 1024;                             // byte offset in 8KB group

  // ---- fragment read addressing (swizzled): row r, granule (lane>>4)^s(r&15) ----
  const int rswz = (l15 & 3) ^ ((l15 >> 2) & 3);
  const int kgr  = (((lane >> 4) ^ rswz) & 3) * 16;        // byte offset within 64B row
  const int arowb = (wm * 128 + l15) * BK;                 // byte base, mf stride 16*BK
  const int browb = (wn * 64 + l15) * BK;

  i32x4 acc[8][4] = {};

  // One tile: 12 reads + A-stage + lgkm-drain + BAR1 + B-stage + 32 MFMA + vmcnt(2) + BAR2.
#define TILE(SAC, SBC, SAN, SBN_, KA, KB)                                       \
  {                                                                             \
    i32x4 af[8], bfr[4];                                                        \
    _Pragma("unroll") for (int f = 0; f < 8; ++f)                               \
      af[f] = *reinterpret_cast<const i32x4*>(                                  \
          (SAC) + arowb + f * (16 * BK) + kgr);                                 \
    _Pragma("unroll") for (int nf = 0; nf < 4; ++nf)                            \
      bfr[nf] = *reinterpret_cast<const i32x4*>(                                \
          (SBC) + browb + nf * (16 * BK) + kgr);                                \
    gload_lds16(pA + (KA), (SAN) + ldst);                                       \
    gload_lds16(pA + (size_t)128 * KD + (KA), (SAN) + 8192 + ldst);             \
    asm volatile("s_waitcnt lgkmcnt(0)" ::: "memory");                          \
    asm volatile("s_barrier" ::: "memory");                                     \
    gload_lds16(pB + (KB), (SBN_) + ldst);                                      \
    gload_lds16(pB + (size_t)128 * KD + (KB), (SBN_) + 8192 + ldst);            \
    __builtin_amdgcn_s_setprio(1);                                              \
    _Pragma("unroll") for (int f = 0; f < 8; ++f)                               \
      _Pragma("unroll") for (int nf = 0; nf < 4; ++nf)                          \
        acc[f][nf] = __builtin_amdgcn_mfma_i32_16x16x64_i8(                     \
            af[f], bfr[nf], acc[f][nf], 0, 0, 0);                               \
    __builtin_amdgcn_s_setprio(0);                                              \
    asm volatile("s_waitcnt vmcnt(2)" ::: "memory");                            \
    asm volatile("s_barrier" ::: "memory");                                     \
  }

  // ---- prologue: A(0)->sA[0], B(0)->sB[0], B(1)->sB[1]; retire A0,B0 (B1 in flight) ----
  gload_lds16(pA,                        &sA[0][ldst]);
  gload_lds16(pA + (size_t)128 * KD,     &sA[0][8192 + ldst]);
  gload_lds16(pB,                        &sB[0][ldst]);
  gload_lds16(pB + (size_t)128 * KD,     &sB[0][8192 + ldst]);
  gload_lds16(pB + BK,                   &sB[1][ldst]);
  gload_lds16(pB + (size_t)128 * KD + BK, &sB[1][8192 + ldst]);
  asm volatile("s_waitcnt vmcnt(2)" ::: "memory");
  asm volatile("s_barrier" ::: "memory");

  for (int j = 0; j < NT / 2; ++j) {
    const int kA1 = (2 * j + 1) * BK;                           // tile 2j+1 (always real)
    const int kB2 = (2 * j + 2 < NT) ? (2 * j + 2) * BK : 0;    // dead-wrap at end
    const int kB3 = (2 * j + 3 < NT) ? (2 * j + 3) * BK : 0;

    // tile 2j (buf0): stage A(2j+1)->sA[1], B(2j+2)->sB[0]
    TILE(&sA[0][0], &sB[0][0], &sA[1][0], &sB[0][0], kA1, kB2)
    // tile 2j+1 (buf1): stage A(2j+2)->sA[0], B(2j+3)->sB[1]
    TILE(&sA[1][0], &sB[1][0], &sA[0][0], &sB[1][0], kB2, kB3)
  }
#undef TILE

  // ---- epilogue (C/D layout dtype-independent: col=l15, row=(lane>>4)*4+jj) ----
  const int crow = m0 + wm * 128 + (lane >> 4) * 4;
  const int ccol = n0 + wn * 64 + l15;
  if (use_slab) {
    int* Cz = Cout + (size_t)z * C_ELEMS;
#pragma unroll
    for (int mf = 0; mf < 8; ++mf)
#pragma unroll
      for (int nf = 0; nf < 4; ++nf)
#pragma unroll
        for (int jj = 0; jj < 4; ++jj)
          Cz[(size_t)(crow + mf * 16 + jj) * OUT_F + ccol + nf * 16] = acc[mf][nf][jj];
  } else {
    float* Cf = reinterpret_cast<float*>(Cout);
#pragma unroll
    for (int mf = 0; mf < 8; ++mf)
#pragma unroll
      for (int nf = 0; nf < 4; ++nf)
#pragma unroll
        for (int jj = 0; jj < 4; ++jj)
          atomicAdd(&Cf[(size_t)(crow + mf * 16 + jj) * OUT_F + ccol + nf * 16],
                    (float)acc[mf][nf][jj] * DQ);
  }
}

// ---------------- K-split i32 slab reduce + dequant + bias ----------------
__global__ __launch_bounds__(256) void reduce_kernel(const i32x4* __restrict__ s,
                                                     const float* __restrict__ bias,
                                                     f32x4* __restrict__ y) {
  size_t i = (size_t)blockIdx.x * 256 + threadIdx.x;
  const size_t NQ = C_ELEMS / 4;
  i32x4 v = s[i] + s[i + NQ] + s[i + 2 * NQ] + s[i + 3 * NQ];
  f32x4 bv = reinterpret_cast<const f32x4*>(bias)[i & 255];   // OUT_F/4 = 256 per row
  f32x4 r;
  r[0] = (float)v[0] * DQ + bv[0];
  r[1] = (float)v[1] * DQ + bv[1];
  r[2] = (float)v[2] * DQ + bv[2];
  r[3] = (float)v[3] * DQ + bv[3];
  y[i] = r;
}

// ---------------- bias broadcast (atomic-fallback init): y[b][o] = bias[o] ----------------
__global__ __launch_bounds__(256) void binit_kernel(const float* __restrict__ bias,
                                                    f32x4* __restrict__ y) {
  size_t i = (size_t)blockIdx.x * 256 + threadIdx.x;
  y[i] = reinterpret_cast<const f32x4*>(bias)[i & 255];
}

// ---------------- fallback (no workspace): direct f32 evaluation ----------------
__global__ __launch_bounds__(256) void naive_kernel(const float* __restrict__ x,
                                                    const float* __restrict__ a,
                                                    const float* __restrict__ b,
                                                    float* __restrict__ y) {
  int o  = blockIdx.x * 256 + threadIdx.x;
  int bb = blockIdx.y;
  __shared__ float xs[IN_F];
  for (int i = threadIdx.x; i < IN_F; i += 256) xs[i] = x[(size_t)bb * IN_F + i];
  __syncthreads();
  float acc = 0.f;
  for (int i = 0; i < IN_F; ++i) {
    float s1, c1; sincosf(xs[i], &s1, &c1);
    float sk = 0.f, ck = 1.f;
    const float* ap = a + (size_t)o * 8192 + i * KF;
    const float* bp = b + (size_t)o * 8192 + i * KF;
#pragma unroll
    for (int k = 0; k < KF; ++k) {
      acc += sk * ap[k] + ck * bp[k];
      float sn = sk * c1 + ck * s1;
      ck = ck * c1 - sk * s1;
      sk = sn;
    }
  }
  y[(size_t)bb * OUT_F + o] = acc;
}

extern "C" void kernel_launch(void* const* d_in, const int* in_sizes, int n_in,
                              void* d_out, int out_size, void* d_ws, size_t ws_size,
                              hipStream_t stream) {
  (void)in_sizes; (void)n_in; (void)out_size;
  const float* x = (const float*)d_in[0];
  const float* a = (const float*)d_in[1];
  const float* b = (const float*)d_in[2];
  float* y = (float*)d_out;

  const size_t XQ_BYTES   = (size_t)BATCH * KD;                            // 56 MiB
  const size_t WQ_BYTES   = (size_t)OUT_F * KD;                            // 14 MiB
  const size_t BIAS_BYTES = (size_t)OUT_F * sizeof(float);                 // 4 KiB
  const size_t SLAB_BYTES = C_ELEMS * sizeof(int) * KSPLIT;                // 64 MiB

  if (ws_size >= XQ_BYTES + WQ_BYTES + BIAS_BYTES) {
    signed char* Xq = (signed char*)d_ws;
    signed char* Wq = (signed char*)d_ws + XQ_BYTES;
    float* bias     = (float*)((char*)d_ws + XQ_BYTES + WQ_BYTES);
    int* slabs      = (int*)((char*)d_ws + XQ_BYTES + WQ_BYTES + BIAS_BYTES);
    const bool slab = ws_size >= XQ_BYTES + WQ_BYTES + BIAS_BYTES + SLAB_BYTES;

    wconv_kernel<<<OUT_F, 256, 0, stream>>>(a, b, Wq, bias);
    feat_kernel<<<(BATCH * IN_F / 4) / 256, 256, 0, stream>>>(x, Xq);
    if (slab) {
      gemm_kernel<<<dim3((BATCH / BM) * (OUT_F / BN) * KSPLIT), 512, 0, stream>>>(Xq, Wq, slabs, 1);
      reduce_kernel<<<(int)(C_ELEMS / 4 / 256), 256, 0, stream>>>((const i32x4*)slabs, bias, (f32x4*)y);
    } else {
      binit_kernel<<<(int)(C_ELEMS / 4 / 256), 256, 0, stream>>>(bias, (f32x4*)y);
      gemm_kernel<<<dim3((BATCH / BM) * (OUT_F / BN) * KSPLIT), 512, 0, stream>>>(Xq, Wq, (int*)y, 0);
    }
  } else {
    naive_kernel<<<dim3(OUT_F / 256, BATCH), 256, 0, stream>>>(x, a, b, y);
  }
}

// Round 23
// 109.973 us; speedup vs baseline: 1.1739x; 1.0275x over previous
//
#include <hip/hip_runtime.h>

#define BATCH   4096
#define IN_F    1024
#define OUT_F   1024
#define KF      8
#define KD      14336          /* K-dim in i8 elements (= bytes), feature-major, k=0 trimmed */

#define BM 256
#define BN 256
#define BK 64                  /* K per tile (bytes) */
#define KSPLIT 4
#define KCHUNK (KD/KSPLIT)     /* 3584 */
#define NT (KCHUNK/BK)         /* 56 K-tiles per block (even) */
#define C_ELEMS ((size_t)BATCH * OUT_F)

#define QW 1040384.0f          /* 127 * 8192: w stored as raw/8192 -> q = rint(w*QW) */
#define DQ (1.0f/132128768.0f) /* 1/(127*127*8192) */

typedef int   i32x4 __attribute__((ext_vector_type(4)));
typedef float f32x4 __attribute__((ext_vector_type(4)));

__device__ __forceinline__ void gload_lds16(const void* g, void* l) {
  __builtin_amdgcn_global_load_lds((const __attribute__((address_space(1))) void*)g,
                                   (__attribute__((address_space(3))) void*)l,
                                   16, 0, 0);
}

__device__ __forceinline__ unsigned int pack4(int q0, int q1, int q2, int q3) {
  return (unsigned int)(q0 & 255) | ((unsigned int)(q1 & 255) << 8) |
         ((unsigned int)(q2 & 255) << 16) | ((unsigned int)(q3 & 255) << 24);
}

// ---------------- W quantization (k=0 trimmed, feature-major, i-quad) + bias ----------------
__global__ __launch_bounds__(256) void wconv_kernel(const float* __restrict__ a,
                                                    const float* __restrict__ b,
                                                    signed char* __restrict__ W,
                                                    float* __restrict__ bias) {
  const int o  = blockIdx.x;
  const int i0 = threadIdx.x * 4;
  const float4* ap = reinterpret_cast<const float4*>(a + (size_t)o * 8192 + i0 * 8);
  const float4* bp = reinterpret_cast<const float4*>(b + (size_t)o * 8192 + i0 * 8);
  union { float4 v[2]; float f[8]; } ua[4], ub[4];
#pragma unroll
  for (int ii = 0; ii < 4; ++ii) {
    ua[ii].v[0] = ap[2 * ii]; ua[ii].v[1] = ap[2 * ii + 1];
    ub[ii].v[0] = bp[2 * ii]; ub[ii].v[1] = bp[2 * ii + 1];
  }
  unsigned int* wp = reinterpret_cast<unsigned int*>(W + (size_t)o * KD + i0);
#pragma unroll
  for (int j = 0; j < 7; ++j) {
    int qa[4], qb[4];
#pragma unroll
    for (int ii = 0; ii < 4; ++ii) {
      qa[ii] = __float2int_rn(ua[ii].f[j + 1] * QW);
      qb[ii] = __float2int_rn(ub[ii].f[j + 1] * QW);
    }
    wp[j       * (IN_F / 4)] = pack4(qa[0], qa[1], qa[2], qa[3]);
    wp[(7 + j) * (IN_F / 4)] = pack4(qb[0], qb[1], qb[2], qb[3]);
  }
  float bsum = ub[0].f[0] + ub[1].f[0] + ub[2].f[0] + ub[3].f[0];
#pragma unroll
  for (int off = 32; off > 0; off >>= 1) bsum += __shfl_down(bsum, off);
  __shared__ float red[4];
  if ((threadIdx.x & 63) == 0) red[threadIdx.x >> 6] = bsum;
  __syncthreads();
  if (threadIdx.x == 0) bias[o] = red[0] + red[1] + red[2] + red[3];
}

// ---------------- feature kernel (feature-major, i-quad): Xq[b][j*1024+i] i8 ----------------
__global__ __launch_bounds__(256) void feat_kernel(const float* __restrict__ x,
                                                   signed char* __restrict__ Xq) {
  int idx = blockIdx.x * 256 + threadIdx.x;
  int bb = idx >> 8;
  int i0 = (idx & 255) * 4;
  float4 xv = *reinterpret_cast<const float4*>(x + (size_t)bb * IN_F + i0);
  float sv[4][KF], cv[4][KF];
#pragma unroll
  for (int ii = 0; ii < 4; ++ii) {
    float xx = (ii == 0) ? xv.x : (ii == 1) ? xv.y : (ii == 2) ? xv.z : xv.w;
    sincosf(xx, &sv[ii][1], &cv[ii][1]);
#pragma unroll
    for (int k = 2; k < KF; ++k) {
      sv[ii][k] = sv[ii][k-1] * cv[ii][1] + cv[ii][k-1] * sv[ii][1];
      cv[ii][k] = cv[ii][k-1] * cv[ii][1] - sv[ii][k-1] * sv[ii][1];
    }
  }
  unsigned int* dst = reinterpret_cast<unsigned int*>(Xq + (size_t)bb * KD + i0);
#pragma unroll
  for (int j = 0; j < 7; ++j) {
    dst[j * (IN_F / 4)] = pack4(__float2int_rn(127.f * sv[0][j+1]), __float2int_rn(127.f * sv[1][j+1]),
                                __float2int_rn(127.f * sv[2][j+1]), __float2int_rn(127.f * sv[3][j+1]));
    dst[(7 + j) * (IN_F / 4)] = pack4(__float2int_rn(127.f * cv[0][j+1]), __float2int_rn(127.f * cv[1][j+1]),
                                      __float2int_rn(127.f * cv[2][j+1]), __float2int_rn(127.f * cv[3][j+1]));
  }
}

// ---------------- GEMM: i8 256x256, 8 waves, 2 barriers/tile, bf-first counted lgkm ----------
// R20 (74.6us best) with one refinement: only the 4 bf reads must complete before BAR1
// (B-stage overwrites their source sB[cur]); the 8 af reads source sA[cur] which is not
// overwritten until next tile's post-BAR2 A-stage, and their MFMA consumption is guarded
// by compiler counted-lgkm waits. LDS ops retire in order -> issue bf FIRST (pinned by
// sched_barrier(0)), then af, then lgkmcnt(8) = oldest-4 (bf) retired; af stays in
// flight across BAR1 and lands under B-stage issue + MFMA head. vmcnt ledger identical
// to R20 (A-stage pre-BAR1, B-stage post-BAR1, vmcnt(2)@BAR2, never 0).
// Pre-commit: GEMM >= 74.5us or absmax change -> revert to R20.
__global__ __launch_bounds__(512, 2) void gemm_kernel(const signed char* __restrict__ A,
                                                      const signed char* __restrict__ Bt,
                                                      int* __restrict__ Cout,
                                                      int use_slab) {
  __shared__ signed char sA[2][BM * BK];   // 16 KiB each
  __shared__ signed char sB[2][BN * BK];

  const int tid  = threadIdx.x;
  const int wid  = tid >> 6;
  const int lane = tid & 63;
  const int wm = wid >> 2, wn = wid & 3;
  const int l15 = lane & 15;

  // bijective XCD swizzle: 256 blocks % 8 XCDs == 0; 32 consecutive work items/XCD
  const int bid = blockIdx.x;
  const int s   = (bid & 7) * 32 + (bid >> 3);
  const int z   = s >> 6;          // K-split chunk 0..3
  const int mt  = s & 15;          // m-tile fastest -> XCD shares W panels in L2
  const int nt  = (s >> 4) & 3;
  const int m0  = mt * BM;
  const int n0  = nt * BN;
  const int fbase = z * KCHUNK;

  // ---- staging addressing: 4 lanes/row (16B granules), 16 rows/wave, 128 rows/gload ----
  const int srow = wid * 16 + (lane >> 2);                 // row 0..127 within group
  const int swz  = ((lane >> 2) & 3) ^ ((lane >> 4) & 3);  // s(row) = (r&3)^((r>>2)&3)
  const int gsrc = (lane & 3) ^ swz;                       // pre-swizzled source granule
  const signed char* pA = A  + (size_t)(m0 + srow) * KD + fbase + gsrc * 16;
  const signed char* pB = Bt + (size_t)(n0 + srow) * KD + fbase + gsrc * 16;
  const int ldst = wid * 1024;                             // byte offset in 8KB group

  // ---- fragment read addressing (swizzled): row r, granule (lane>>4)^s(r&15) ----
  const int rswz = (l15 & 3) ^ ((l15 >> 2) & 3);
  const int kgr  = (((lane >> 4) ^ rswz) & 3) * 16;        // byte offset within 64B row
  const int arowb = (wm * 128 + l15) * BK;                 // byte base, mf stride 16*BK
  const int browb = (wn * 64 + l15) * BK;

  i32x4 acc[8][4] = {};

  // One tile: bf x4 (pinned first) + af x8 + A-stage + lgkmcnt(8) + BAR1 + B-stage +
  // 32 MFMA + vmcnt(2) + BAR2.
#define TILE(SAC, SBC, SAN, SBN_, KA, KB)                                       \
  {                                                                             \
    i32x4 af[8], bfr[4];                                                        \
    _Pragma("unroll") for (int nf = 0; nf < 4; ++nf)                            \
      bfr[nf] = *reinterpret_cast<const i32x4*>(                                \
          (SBC) + browb + nf * (16 * BK) + kgr);                                \
    __builtin_amdgcn_sched_barrier(0);                                          \
    _Pragma("unroll") for (int f = 0; f < 8; ++f)                               \
      af[f] = *reinterpret_cast<const i32x4*>(                                  \
          (SAC) + arowb + f * (16 * BK) + kgr);                                 \
    gload_lds16(pA + (KA), (SAN) + ldst);                                       \
    gload_lds16(pA + (size_t)128 * KD + (KA), (SAN) + 8192 + ldst);             \
    asm volatile("s_waitcnt lgkmcnt(8)" ::: "memory");                          \
    asm volatile("s_barrier" ::: "memory");                                     \
    gload_lds16(pB + (KB), (SBN_) + ldst);                                      \
    gload_lds16(pB + (size_t)128 * KD + (KB), (SBN_) + 8192 + ldst);            \
    __builtin_amdgcn_s_setprio(1);                                              \
    _Pragma("unroll") for (int f = 0; f < 8; ++f)                               \
      _Pragma("unroll") for (int nf = 0; nf < 4; ++nf)                          \
        acc[f][nf] = __builtin_amdgcn_mfma_i32_16x16x64_i8(                     \
            af[f], bfr[nf], acc[f][nf], 0, 0, 0);                               \
    __builtin_amdgcn_s_setprio(0);                                              \
    asm volatile("s_waitcnt vmcnt(2)" ::: "memory");                            \
    asm volatile("s_barrier" ::: "memory");                                     \
  }

  // ---- prologue: A(0)->sA[0], B(0)->sB[0], B(1)->sB[1]; retire A0,B0 (B1 in flight) ----
  gload_lds16(pA,                        &sA[0][ldst]);
  gload_lds16(pA + (size_t)128 * KD,     &sA[0][8192 + ldst]);
  gload_lds16(pB,                        &sB[0][ldst]);
  gload_lds16(pB + (size_t)128 * KD,     &sB[0][8192 + ldst]);
  gload_lds16(pB + BK,                   &sB[1][ldst]);
  gload_lds16(pB + (size_t)128 * KD + BK, &sB[1][8192 + ldst]);
  asm volatile("s_waitcnt vmcnt(2)" ::: "memory");
  asm volatile("s_barrier" ::: "memory");

  for (int j = 0; j < NT / 2; ++j) {
    const int kA1 = (2 * j + 1) * BK;                           // tile 2j+1 (always real)
    const int kB2 = (2 * j + 2 < NT) ? (2 * j + 2) * BK : 0;    // dead-wrap at end
    const int kB3 = (2 * j + 3 < NT) ? (2 * j + 3) * BK : 0;

    // tile 2j (buf0): stage A(2j+1)->sA[1], B(2j+2)->sB[0]
    TILE(&sA[0][0], &sB[0][0], &sA[1][0], &sB[0][0], kA1, kB2)
    // tile 2j+1 (buf1): stage A(2j+2)->sA[0], B(2j+3)->sB[1]
    TILE(&sA[1][0], &sB[1][0], &sA[0][0], &sB[1][0], kB2, kB3)
  }
#undef TILE

  // ---- epilogue (C/D layout dtype-independent: col=l15, row=(lane>>4)*4+jj) ----
  const int crow = m0 + wm * 128 + (lane >> 4) * 4;
  const int ccol = n0 + wn * 64 + l15;
  if (use_slab) {
    int* Cz = Cout + (size_t)z * C_ELEMS;
#pragma unroll
    for (int mf = 0; mf < 8; ++mf)
#pragma unroll
      for (int nf = 0; nf < 4; ++nf)
#pragma unroll
        for (int jj = 0; jj < 4; ++jj)
          Cz[(size_t)(crow + mf * 16 + jj) * OUT_F + ccol + nf * 16] = acc[mf][nf][jj];
  } else {
    float* Cf = reinterpret_cast<float*>(Cout);
#pragma unroll
    for (int mf = 0; mf < 8; ++mf)
#pragma unroll
      for (int nf = 0; nf < 4; ++nf)
#pragma unroll
        for (int jj = 0; jj < 4; ++jj)
          atomicAdd(&Cf[(size_t)(crow + mf * 16 + jj) * OUT_F + ccol + nf * 16],
                    (float)acc[mf][nf][jj] * DQ);
  }
}

// ---------------- K-split i32 slab reduce + dequant + bias ----------------
__global__ __launch_bounds__(256) void reduce_kernel(const i32x4* __restrict__ s,
                                                     const float* __restrict__ bias,
                                                     f32x4* __restrict__ y) {
  size_t i = (size_t)blockIdx.x * 256 + threadIdx.x;
  const size_t NQ = C_ELEMS / 4;
  i32x4 v = s[i] + s[i + NQ] + s[i + 2 * NQ] + s[i + 3 * NQ];
  f32x4 bv = reinterpret_cast<const f32x4*>(bias)[i & 255];   // OUT_F/4 = 256 per row
  f32x4 r;
  r[0] = (float)v[0] * DQ + bv[0];
  r[1] = (float)v[1] * DQ + bv[1];
  r[2] = (float)v[2] * DQ + bv[2];
  r[3] = (float)v[3] * DQ + bv[3];
  y[i] = r;
}

// ---------------- bias broadcast (atomic-fallback init): y[b][o] = bias[o] ----------------
__global__ __launch_bounds__(256) void binit_kernel(const float* __restrict__ bias,
                                                    f32x4* __restrict__ y) {
  size_t i = (size_t)blockIdx.x * 256 + threadIdx.x;
  y[i] = reinterpret_cast<const f32x4*>(bias)[i & 255];
}

// ---------------- fallback (no workspace): direct f32 evaluation ----------------
__global__ __launch_bounds__(256) void naive_kernel(const float* __restrict__ x,
                                                    const float* __restrict__ a,
                                                    const float* __restrict__ b,
                                                    float* __restrict__ y) {
  int o  = blockIdx.x * 256 + threadIdx.x;
  int bb = blockIdx.y;
  __shared__ float xs[IN_F];
  for (int i = threadIdx.x; i < IN_F; i += 256) xs[i] = x[(size_t)bb * IN_F + i];
  __syncthreads();
  float acc = 0.f;
  for (int i = 0; i < IN_F; ++i) {
    float s1, c1; sincosf(xs[i], &s1, &c1);
    float sk = 0.f, ck = 1.f;
    const float* ap = a + (size_t)o * 8192 + i * KF;
    const float* bp = b + (size_t)o * 8192 + i * KF;
#pragma unroll
    for (int k = 0; k < KF; ++k) {
      acc += sk * ap[k] + ck * bp[k];
      float sn = sk * c1 + ck * s1;
      ck = ck * c1 - sk * s1;
      sk = sn;
    }
  }
  y[(size_t)bb * OUT_F + o] = acc;
}

extern "C" void kernel_launch(void* const* d_in, const int* in_sizes, int n_in,
                              void* d_out, int out_size, void* d_ws, size_t ws_size,
                              hipStream_t stream) {
  (void)in_sizes; (void)n_in; (void)out_size;
  const float* x = (const float*)d_in[0];
  const float* a = (const float*)d_in[1];
  const float* b = (const float*)d_in[2];
  float* y = (float*)d_out;

  const size_t XQ_BYTES   = (size_t)BATCH * KD;                            // 56 MiB
  const size_t WQ_BYTES   = (size_t)OUT_F * KD;                            // 14 MiB
  const size_t BIAS_BYTES = (size_t)OUT_F * sizeof(float);                 // 4 KiB
  const size_t SLAB_BYTES = C_ELEMS * sizeof(int) * KSPLIT;                // 64 MiB

  if (ws_size >= XQ_BYTES + WQ_BYTES + BIAS_BYTES) {
    signed char* Xq = (signed char*)d_ws;
    signed char* Wq = (signed char*)d_ws + XQ_BYTES;
    float* bias     = (float*)((char*)d_ws + XQ_BYTES + WQ_BYTES);
    int* slabs      = (int*)((char*)d_ws + XQ_BYTES + WQ_BYTES + BIAS_BYTES);
    const bool slab = ws_size >= XQ_BYTES + WQ_BYTES + BIAS_BYTES + SLAB_BYTES;

    wconv_kernel<<<OUT_F, 256, 0, stream>>>(a, b, Wq, bias);
    feat_kernel<<<(BATCH * IN_F / 4) / 256, 256, 0, stream>>>(x, Xq);
    if (slab) {
      gemm_kernel<<<dim3((BATCH / BM) * (OUT_F / BN) * KSPLIT), 512, 0, stream>>>(Xq, Wq, slabs, 1);
      reduce_kernel<<<(int)(C_ELEMS / 4 / 256), 256, 0, stream>>>((const i32x4*)slabs, bias, (f32x4*)y);
    } else {
      binit_kernel<<<(int)(C_ELEMS / 4 / 256), 256, 0, stream>>>(bias, (f32x4*)y);
      gemm_kernel<<<dim3((BATCH / BM) * (OUT_F / BN) * KSPLIT), 512, 0, stream>>>(Xq, Wq, (int*)y, 0);
    }
  } else {
    naive_kernel<<<dim3(OUT_F / 256, BATCH), 256, 0, stream>>>(x, a, b, y);
  }
}